// Round 1
// baseline (163.453 us; speedup 1.0000x reference)
//
#include <hip/hip_runtime.h>

#define B_  16
#define TQ  128
#define TK  256
#define DIN 64
#define H_  256
#define DV  256
#define HT  16
#define NEG -1000000.0f

// ---------------- Kernel A: qp[b,q,h] = sum_d queries[b,q,d]*wq[d,h] ----------------
// grid = B*TQ blocks, 256 threads (t = h). queries row broadcast (scalar loads),
// wq reads + qp writes coalesced.
__global__ __launch_bounds__(256) void proj_q_kernel(
    const float* __restrict__ queries, const float* __restrict__ wq,
    float* __restrict__ qp)
{
    int bq = blockIdx.x;           // b*TQ + q
    int h  = threadIdx.x;
    const float* qrow = queries + bq * DIN;
    float acc = 0.f;
    #pragma unroll
    for (int d = 0; d < DIN; ++d)
        acc = fmaf(qrow[d], wq[d * H_ + h], acc);
    qp[bq * H_ + h] = acc;
}

// ---------------- Kernel B: kpT[b,h,k] = sum_d keys[b,k,d]*wk[d,h] ----------------
// grid = B*(H/HT) blocks, 256 threads (t = k). Writes transposed layout, coalesced
// over k. keys reads are per-thread contiguous (L1-friendly); wk reads are scalar.
__global__ __launch_bounds__(256) void proj_k_kernel(
    const float* __restrict__ keys, const float* __restrict__ wk,
    float* __restrict__ kpT)
{
    int b  = blockIdx.x >> 4;            // H_/HT == 16
    int h0 = (blockIdx.x & 15) * HT;
    int t  = threadIdx.x;                // k index
    const float* krow = keys + (b * TK + t) * DIN;
    float acc[HT];
    #pragma unroll
    for (int hh = 0; hh < HT; ++hh) acc[hh] = 0.f;
    #pragma unroll 4
    for (int d = 0; d < DIN; ++d) {
        float kv = krow[d];
        #pragma unroll
        for (int hh = 0; hh < HT; ++hh)
            acc[hh] = fmaf(kv, wk[d * H_ + h0 + hh], acc[hh]);
    }
    #pragma unroll
    for (int hh = 0; hh < HT; ++hh)
        kpT[(b * H_ + h0 + hh) * TK + t] = acc[hh];
}

// ---------------- wave/block reductions ----------------
__device__ inline float waveMax(float v) {
    #pragma unroll
    for (int off = 32; off > 0; off >>= 1) v = fmaxf(v, __shfl_xor(v, off, 64));
    return v;
}
__device__ inline float waveSum(float v) {
    #pragma unroll
    for (int off = 32; off > 0; off >>= 1) v += __shfl_xor(v, off, 64);
    return v;
}

// ---------------- Kernel C: fused scores + masked softmax + attn@V ----------------
// grid = B*TQ blocks (one per query row), 256 threads.
// Phase 1 (t = k): score_t = sum_h tanh(qp[h] + kpT[b,h,t]) * wv[h]  (kpT coalesced)
// Phase 2: masked softmax across the block (4 waves)
// Phase 3 (t = v): out[b,q,t] = sum_k attn[k] * values[b,k,t]        (values coalesced)
__global__ __launch_bounds__(256) void attn_kernel(
    const float* __restrict__ qp, const float* __restrict__ kpT,
    const float* __restrict__ values, const int* __restrict__ valid_lens,
    const float* __restrict__ wv, float* __restrict__ out)
{
    __shared__ float qLDS[H_];
    __shared__ float wvLDS[H_];
    __shared__ float attnLDS[TK];
    __shared__ float red[8];

    int b = blockIdx.x / TQ;
    int q = blockIdx.x % TQ;
    int t = threadIdx.x;

    qLDS[t]  = qp[(b * TQ + q) * H_ + t];
    wvLDS[t] = wv[t];
    __syncthreads();

    // ---- scores ----
    const float* kcol = kpT + b * H_ * TK + t;
    float s = 0.f;
    #pragma unroll 8
    for (int h = 0; h < H_; ++h) {
        float x = qLDS[h] + kcol[h * TK];
        // tanh(x) = 1 - 2/(exp(2x)+1); exact at +-inf, ~1e-6 rel err via v_exp_f32
        float e = __expf(2.f * x);
        float th = 1.f - 2.f / (e + 1.f);
        s = fmaf(wvLDS[h], th, s);
    }

    int vl = valid_lens[b];
    float sc = (t < vl) ? s : NEG;

    // ---- masked softmax across 256 threads (4 waves) ----
    int wid = t >> 6;
    float m = waveMax(sc);
    if ((t & 63) == 0) red[wid] = m;
    __syncthreads();
    m = fmaxf(fmaxf(red[0], red[1]), fmaxf(red[2], red[3]));

    float p = __expf(sc - m);
    float ws = waveSum(p);
    if ((t & 63) == 0) red[4 + wid] = ws;   // disjoint slots: no hazard with red[0..3] reads
    __syncthreads();
    float denom = red[4] + red[5] + red[6] + red[7];

    attnLDS[t] = p / denom;
    __syncthreads();

    // ---- attn @ values ----
    const float* vcol = values + b * TK * DV + t;
    float acc = 0.f;
    #pragma unroll 8
    for (int k = 0; k < TK; ++k)
        acc = fmaf(attnLDS[k], vcol[k * DV], acc);
    out[(b * TQ + q) * DV + t] = acc;
}

extern "C" void kernel_launch(void* const* d_in, const int* in_sizes, int n_in,
                              void* d_out, int out_size, void* d_ws, size_t ws_size,
                              hipStream_t stream) {
    const float* queries    = (const float*)d_in[0];
    const float* keys       = (const float*)d_in[1];
    const float* values     = (const float*)d_in[2];
    const int*   valid_lens = (const int*)  d_in[3];
    const float* wq         = (const float*)d_in[4];
    const float* wk         = (const float*)d_in[5];
    const float* wv         = (const float*)d_in[6];
    float* out = (float*)d_out;

    // workspace layout: qp [B,TQ,H] then kpT [B,H,TK]
    float* qp  = (float*)d_ws;                       // 16*128*256*4 = 2 MiB
    float* kpT = qp + (size_t)B_ * TQ * H_;          // 16*256*256*4 = 4 MiB

    proj_q_kernel<<<B_ * TQ, 256, 0, stream>>>(queries, wq, qp);
    proj_k_kernel<<<B_ * (H_ / HT), 256, 0, stream>>>(keys, wk, kpT);
    attn_kernel<<<B_ * TQ, 256, 0, stream>>>(qp, kpT, values, valid_lens, wv, out);
}

// Round 2
// 129.840 us; speedup vs baseline: 1.2589x; 1.2589x over previous
//
#include <hip/hip_runtime.h>

#define B_  16
#define TQ  128
#define TK  256
#define DIN 64
#define H_  256
#define DV  256
#define HT  16
#define NEG -1000000.0f

// 2*log2(e): tanh(x) = 1 - 2/(1+e^{2x}) = 1 - 2*rcp(1 + exp2(SCALE*x))
#define SCALE  2.8853900817779268f
#define LOG2E  1.4426950408889634f

// raw v_exp_f32 / v_rcp_f32 (avoid IEEE-division expansion; ~1 ulp, fine vs 2e-2 threshold)
__device__ inline float fast_exp2(float x) { return __builtin_amdgcn_exp2f(x); }
__device__ inline float fast_rcp(float x)  { return __builtin_amdgcn_rcpf(x); }

// ---------------- Kernel B: kpT[b,h,k] = SCALE * sum_d keys[b,k,d]*wk[d,h] ----------------
// grid = B*(H/HT) blocks, 256 threads (t = k). Transposed + pre-scaled by 2*log2(e).
__global__ __launch_bounds__(256) void proj_k_kernel(
    const float* __restrict__ keys, const float* __restrict__ wk,
    float* __restrict__ kpT)
{
    int b  = blockIdx.x >> 4;            // H_/HT == 16
    int h0 = (blockIdx.x & 15) * HT;
    int t  = threadIdx.x;                // k index
    const float* krow = keys + (b * TK + t) * DIN;
    float acc[HT];
    #pragma unroll
    for (int hh = 0; hh < HT; ++hh) acc[hh] = 0.f;
    #pragma unroll 4
    for (int d = 0; d < DIN; ++d) {
        float kv = krow[d];
        #pragma unroll
        for (int hh = 0; hh < HT; ++hh)
            acc[hh] = fmaf(kv, wk[d * H_ + h0 + hh], acc[hh]);
    }
    #pragma unroll
    for (int hh = 0; hh < HT; ++hh)
        kpT[(b * H_ + h0 + hh) * TK + t] = acc[hh] * SCALE;
}

// ---------------- wave/block reductions ----------------
__device__ inline float waveMax(float v) {
    #pragma unroll
    for (int off = 32; off > 0; off >>= 1) v = fmaxf(v, __shfl_xor(v, off, 64));
    return v;
}
__device__ inline float waveSum(float v) {
    #pragma unroll
    for (int off = 32; off > 0; off >>= 1) v += __shfl_xor(v, off, 64);
    return v;
}

// ---------------- Kernel C: fused q-proj + scores + masked softmax + attn@V ----------------
// grid = B*TQ blocks (one per query row), 256 threads.
// Phase 0 (t = h): qw[t] = { SCALE * sum_d queries[b,q,d]*wq[d,t], wv[t] }
// Phase 1 (t = k): score_t = sum_h tanh-term via exp2/rcp      (kpT coalesced)
// Phase 2: masked softmax across the block (4 waves)
// Phase 3 (t = v): out[b,q,t] = sum_k attn[k] * values[b,k,t]  (values coalesced)
__global__ __launch_bounds__(256) void attn_kernel(
    const float* __restrict__ queries, const float* __restrict__ wq,
    const float* __restrict__ kpT,
    const float* __restrict__ values, const int* __restrict__ valid_lens,
    const float* __restrict__ wv, float* __restrict__ out)
{
    __shared__ float2 qw[H_];        // .x = scaled q-projection, .y = wv — one ds_read_b64/iter
    __shared__ float attnLDS[TK];
    __shared__ float red[8];

    int b = blockIdx.x / TQ;
    int q = blockIdx.x % TQ;
    int t = threadIdx.x;

    // ---- fused q projection (t = h) ----
    {
        const float* qrow = queries + (b * TQ + q) * DIN;   // uniform -> s_load
        float acc = 0.f;
        #pragma unroll
        for (int d = 0; d < DIN; ++d)
            acc = fmaf(qrow[d], wq[d * H_ + t], acc);       // wq coalesced, L2-hot
        qw[t] = make_float2(acc * SCALE, wv[t]);
    }
    __syncthreads();

    // ---- scores (t = k) ----
    const float* kcol = kpT + b * H_ * TK + t;
    float s = 0.f;
    #pragma unroll 8
    for (int h = 0; h < H_; ++h) {
        float2 c = qw[h];                      // broadcast ds_read_b64
        float u  = c.x + kcol[h * TK];         // = SCALE * (qp + kp)
        float e  = fast_exp2(u);               // v_exp_f32
        float r  = fast_rcp(e + 1.f);          // v_rcp_f32
        float th = fmaf(-2.f, r, 1.f);         // tanh
        s = fmaf(c.y, th, s);
    }

    int vl = valid_lens[b];
    float sc = (t < vl) ? s : NEG;

    // ---- masked softmax across 256 threads (4 waves) ----
    int wid = t >> 6;
    float m = waveMax(sc);
    if ((t & 63) == 0) red[wid] = m;
    __syncthreads();
    m = fmaxf(fmaxf(red[0], red[1]), fmaxf(red[2], red[3]));

    float p = fast_exp2((sc - m) * LOG2E);
    float ws = waveSum(p);
    if ((t & 63) == 0) red[4 + wid] = ws;      // disjoint slots vs red[0..3]
    __syncthreads();
    float denomr = fast_rcp(red[4] + red[5] + red[6] + red[7]);

    attnLDS[t] = p * denomr;
    __syncthreads();

    // ---- attn @ values (t = v) ----
    const float* vcol = values + b * TK * DV + t;
    float acc = 0.f;
    #pragma unroll 8
    for (int k = 0; k < TK; ++k)
        acc = fmaf(attnLDS[k], vcol[k * DV], acc);
    out[(b * TQ + q) * DV + t] = acc;
}

extern "C" void kernel_launch(void* const* d_in, const int* in_sizes, int n_in,
                              void* d_out, int out_size, void* d_ws, size_t ws_size,
                              hipStream_t stream) {
    const float* queries    = (const float*)d_in[0];
    const float* keys       = (const float*)d_in[1];
    const float* values     = (const float*)d_in[2];
    const int*   valid_lens = (const int*)  d_in[3];
    const float* wq         = (const float*)d_in[4];
    const float* wk         = (const float*)d_in[5];
    const float* wv         = (const float*)d_in[6];
    float* out = (float*)d_out;

    // workspace: kpT [B,H,TK] = 4 MiB
    float* kpT = (float*)d_ws;

    proj_k_kernel<<<B_ * (H_ / HT), 256, 0, stream>>>(keys, wk, kpT);
    attn_kernel<<<B_ * TQ, 256, 0, stream>>>(queries, wq, kpT, values, valid_lens, wv, out);
}

// Round 3
// 122.534 us; speedup vs baseline: 1.3339x; 1.0596x over previous
//
#include <hip/hip_runtime.h>

#define B_  16
#define TQ  128
#define TK  256
#define DIN 64
#define H_  256
#define DV  256
#define HT  16
#define QT  4          // q-rows per block == waves per block (phase-2 wave-per-row)
#define NEG -1000000.0f

// 2*log2(e): tanh(x) = 1 - 2/(1+e^{2x}) = 1 - 2*rcp(1 + exp2(SCALE*x))
#define SCALE  2.8853900817779268f
#define LOG2E  1.4426950408889634f

__device__ inline float fast_exp2(float x) { return __builtin_amdgcn_exp2f(x); }
__device__ inline float fast_rcp(float x)  { return __builtin_amdgcn_rcpf(x); }

// ---------------- Kernel B: kpT[b,h,k] = SCALE * sum_d keys[b,k,d]*wk[d,h] ----------------
__global__ __launch_bounds__(256) void proj_k_kernel(
    const float* __restrict__ keys, const float* __restrict__ wk,
    float* __restrict__ kpT)
{
    int b  = blockIdx.x >> 4;            // H_/HT == 16
    int h0 = (blockIdx.x & 15) * HT;
    int t  = threadIdx.x;                // k index
    const float* krow = keys + (b * TK + t) * DIN;
    float acc[HT];
    #pragma unroll
    for (int hh = 0; hh < HT; ++hh) acc[hh] = 0.f;
    #pragma unroll 4
    for (int d = 0; d < DIN; ++d) {
        float kv = krow[d];
        #pragma unroll
        for (int hh = 0; hh < HT; ++hh)
            acc[hh] = fmaf(kv, wk[d * H_ + h0 + hh], acc[hh]);
    }
    #pragma unroll
    for (int hh = 0; hh < HT; ++hh)
        kpT[(b * H_ + h0 + hh) * TK + t] = acc[hh] * SCALE;
}

__device__ inline float waveMax(float v) {
    #pragma unroll
    for (int off = 32; off > 0; off >>= 1) v = fmaxf(v, __shfl_xor(v, off, 64));
    return v;
}
__device__ inline float waveSum(float v) {
    #pragma unroll
    for (int off = 32; off > 0; off >>= 1) v += __shfl_xor(v, off, 64);
    return v;
}

// ---------------- Kernel C: fused q-proj + scores(4 rows) + softmax + attn@V ----------------
// grid = B * (TQ/QT) = 512 blocks, 256 threads. Each block: one batch, QT=4 q-rows.
// Every kpT/values load is reused QT times -> transcendental-bound, 4x less L2 traffic.
__global__ __launch_bounds__(256) void attn_kernel(
    const float* __restrict__ queries, const float* __restrict__ wq,
    const float* __restrict__ kpT,
    const float* __restrict__ values, const int* __restrict__ valid_lens,
    const float* __restrict__ wv, float* __restrict__ out)
{
    __shared__ float4 qs4[H_];          // scaled q-proj, 4 rows packed -> one b128 broadcast
    __shared__ float  wvL[H_];
    __shared__ float  scoreL[QT][TK];
    __shared__ float  attnL[TK][QT];    // k-major -> b128 broadcast in phase 3

    // XCD swizzle: blocks with bx%8==x share an XCD (round-robin heuristic);
    // give each XCD only 2 batches -> 1 MB working set << 4 MiB L2/XCD.
    int bx  = blockIdx.x;
    int xcd = bx & 7;
    int i   = bx >> 3;                  // 0..63
    int b   = xcd + 8 * (i & 1);        // batches {xcd, xcd+8} on this xcd slot
    int q0  = (i >> 1) * QT;            // 0,4,...,124
    int t   = threadIdx.x;

    // ---- phase 0: project 4 query rows (t = h) ----
    {
        const float* qbase = queries + (b * TQ + q0) * DIN;
        float a0 = 0.f, a1 = 0.f, a2 = 0.f, a3 = 0.f;
        #pragma unroll
        for (int d = 0; d < DIN; ++d) {
            float w = wq[d * H_ + t];                 // coalesced, L2-hot
            a0 = fmaf(qbase[d],           w, a0);     // uniform -> scalar loads
            a1 = fmaf(qbase[DIN + d],     w, a1);
            a2 = fmaf(qbase[2 * DIN + d], w, a2);
            a3 = fmaf(qbase[3 * DIN + d], w, a3);
        }
        qs4[t] = make_float4(a0 * SCALE, a1 * SCALE, a2 * SCALE, a3 * SCALE);
        wvL[t] = wv[t];
    }
    __syncthreads();

    // ---- phase 1: scores for 4 rows (t = k); 1 global load amortized over 4 tanh ----
    const float* kcol = kpT + b * H_ * TK + t;
    float s0 = 0.f, s1 = 0.f, s2 = 0.f, s3 = 0.f;
    #pragma unroll 4
    for (int h = 0; h < H_; ++h) {
        float  kv  = kcol[h * TK];      // coalesced over k
        float4 qv  = qs4[h];            // broadcast ds_read_b128
        float  wvh = wvL[h];
        float u0 = qv.x + kv, u1 = qv.y + kv, u2 = qv.z + kv, u3 = qv.w + kv;
        float r0 = fast_rcp(fast_exp2(u0) + 1.f);
        float r1 = fast_rcp(fast_exp2(u1) + 1.f);
        float r2 = fast_rcp(fast_exp2(u2) + 1.f);
        float r3 = fast_rcp(fast_exp2(u3) + 1.f);
        s0 = fmaf(wvh, fmaf(-2.f, r0, 1.f), s0);
        s1 = fmaf(wvh, fmaf(-2.f, r1, 1.f), s1);
        s2 = fmaf(wvh, fmaf(-2.f, r2, 1.f), s2);
        s3 = fmaf(wvh, fmaf(-2.f, r3, 1.f), s3);
    }
    int vl = valid_lens[b];
    bool ok = (t < vl);
    scoreL[0][t] = ok ? s0 : NEG;
    scoreL[1][t] = ok ? s1 : NEG;
    scoreL[2][t] = ok ? s2 : NEG;
    scoreL[3][t] = ok ? s3 : NEG;
    __syncthreads();

    // ---- phase 2: wave w softmaxes row q0+w (4 waves, 4 rows, 2 barriers total) ----
    {
        int w    = t >> 6;
        int lane = t & 63;
        float v0 = scoreL[w][lane];
        float v1 = scoreL[w][lane + 64];
        float v2 = scoreL[w][lane + 128];
        float v3 = scoreL[w][lane + 192];
        float m  = waveMax(fmaxf(fmaxf(v0, v1), fmaxf(v2, v3)));
        float p0 = fast_exp2((v0 - m) * LOG2E);
        float p1 = fast_exp2((v1 - m) * LOG2E);
        float p2 = fast_exp2((v2 - m) * LOG2E);
        float p3 = fast_exp2((v3 - m) * LOG2E);
        float dr = fast_rcp(waveSum(p0 + p1 + p2 + p3));
        attnL[lane      ][w] = p0 * dr;
        attnL[lane + 64 ][w] = p1 * dr;
        attnL[lane + 128][w] = p2 * dr;
        attnL[lane + 192][w] = p3 * dr;
    }
    __syncthreads();

    // ---- phase 3: out rows q0..q0+3 (t = v); 1 values load amortized over 4 FMA ----
    const float* vcol = values + b * TK * DV + t;
    const float4* attn4 = (const float4*)attnL;
    float o0 = 0.f, o1 = 0.f, o2 = 0.f, o3 = 0.f;
    #pragma unroll 8
    for (int k = 0; k < TK; ++k) {
        float  vv = vcol[k * DV];       // coalesced over v
        float4 a  = attn4[k];           // broadcast ds_read_b128
        o0 = fmaf(a.x, vv, o0);
        o1 = fmaf(a.y, vv, o1);
        o2 = fmaf(a.z, vv, o2);
        o3 = fmaf(a.w, vv, o3);
    }
    float* orow = out + (b * TQ + q0) * DV + t;
    orow[0]      = o0;
    orow[DV]     = o1;
    orow[2 * DV] = o2;
    orow[3 * DV] = o3;
}

extern "C" void kernel_launch(void* const* d_in, const int* in_sizes, int n_in,
                              void* d_out, int out_size, void* d_ws, size_t ws_size,
                              hipStream_t stream) {
    const float* queries    = (const float*)d_in[0];
    const float* keys       = (const float*)d_in[1];
    const float* values     = (const float*)d_in[2];
    const int*   valid_lens = (const int*)  d_in[3];
    const float* wq         = (const float*)d_in[4];
    const float* wk         = (const float*)d_in[5];
    const float* wv         = (const float*)d_in[6];
    float* out = (float*)d_out;

    float* kpT = (float*)d_ws;   // [B,H,TK] = 4 MiB

    proj_k_kernel<<<B_ * (H_ / HT), 256, 0, stream>>>(keys, wk, kpT);
    attn_kernel<<<B_ * (TQ / QT), 256, 0, stream>>>(queries, wq, kpT, values,
                                                    valid_lens, wv, out);
}

// Round 4
// 115.953 us; speedup vs baseline: 1.4096x; 1.0568x over previous
//
#include <hip/hip_runtime.h>

#define B_  16
#define TQ  128
#define TK  256
#define DIN 64
#define H_  256
#define DV  256
#define HT  8          // h-cols per proj_k block
#define QT  4          // q-rows per attn block
#define NEG -1000000.0f

// 2*log2(e): tanh(x) = 1 - 2/(1+e^{2x}) = 1 - 2*rcp(1 + exp2(SCALE*x))
#define SCALE  2.8853900817779268f
#define LOG2E  1.4426950408889634f

__device__ inline float fast_exp2(float x) { return __builtin_amdgcn_exp2f(x); }
__device__ inline float fast_rcp(float x)  { return __builtin_amdgcn_rcpf(x); }

// ---------------- Kernel B: kpT[b,h,k] = SCALE * sum_d keys[b,k,d]*wk[d,h] ----------------
// grid = B*(H/HT) = 512 blocks (2/CU), 256 threads (t = k).
__global__ __launch_bounds__(256) void proj_k_kernel(
    const float* __restrict__ keys, const float* __restrict__ wk,
    float* __restrict__ kpT)
{
    int b  = blockIdx.x >> 5;            // H_/HT == 32
    int h0 = (blockIdx.x & 31) * HT;
    int t  = threadIdx.x;                // k index
    const float* krow = keys + (b * TK + t) * DIN;
    float acc[HT];
    #pragma unroll
    for (int hh = 0; hh < HT; ++hh) acc[hh] = 0.f;
    #pragma unroll 4
    for (int d = 0; d < DIN; ++d) {
        float kv = krow[d];
        #pragma unroll
        for (int hh = 0; hh < HT; ++hh)
            acc[hh] = fmaf(kv, wk[d * H_ + h0 + hh], acc[hh]);
    }
    #pragma unroll
    for (int hh = 0; hh < HT; ++hh)
        kpT[(b * H_ + h0 + hh) * TK + t] = acc[hh] * SCALE;
}

__device__ inline float waveMax(float v) {
    #pragma unroll
    for (int off = 32; off > 0; off >>= 1) v = fmaxf(v, __shfl_xor(v, off, 64));
    return v;
}
__device__ inline float waveSum(float v) {
    #pragma unroll
    for (int off = 32; off > 0; off >>= 1) v += __shfl_xor(v, off, 64);
    return v;
}

// ---------------- Kernel C: fused q-proj + scores(4 rows) + softmax + attn@V ----------------
// grid = B*(TQ/QT) = 512 blocks, 512 threads (8 waves -> 16 waves/CU, 2 blocks/CU).
// Phase 1 splits the h-reduction and phase 3 the k-reduction across two half-blocks
// (partials combined in LDS) -> same L2 traffic as R3 but 2x the resident waves.
__global__ __launch_bounds__(512) void attn_kernel(
    const float* __restrict__ queries, const float* __restrict__ wq,
    const float* __restrict__ kpT,
    const float* __restrict__ values, const int* __restrict__ valid_lens,
    const float* __restrict__ wv, float* __restrict__ out)
{
    __shared__ float4 qs4[H_];            // scaled q-proj, 4 rows packed (b128 broadcast)
    __shared__ float  wvL[H_];
    __shared__ float  scoreP[2][QT][TK];  // per-half partial scores; [1] reused for out-partials
    __shared__ float4 attnT[TK];          // attn weights k-major (b128 broadcast in phase 3)

    // XCD swizzle: 2 batches per XCD slot -> ~1 MB working set per XCD L2.
    int bx   = blockIdx.x;
    int xcd  = bx & 7;
    int i    = bx >> 3;                   // 0..63
    int b    = xcd + 8 * (i & 1);
    int q0   = (i >> 1) * QT;             // 0,4,...,124
    int t    = threadIdx.x;               // 0..511
    int half = t >> 8;                    // 0/1: h-range (ph1) / k-range (ph3)
    int lo   = t & 255;                   // k (ph1) or v (ph3) index

    // ---- phase 0: project 4 query rows (first 256 threads, t = h) ----
    if (t < 256) {
        const float* qbase = queries + (b * TQ + q0) * DIN;
        float a0 = 0.f, a1 = 0.f, a2 = 0.f, a3 = 0.f;
        #pragma unroll
        for (int d = 0; d < DIN; ++d) {
            float w = wq[d * H_ + t];                 // coalesced, L2-hot
            a0 = fmaf(qbase[d],           w, a0);     // uniform -> scalar loads
            a1 = fmaf(qbase[DIN + d],     w, a1);
            a2 = fmaf(qbase[2 * DIN + d], w, a2);
            a3 = fmaf(qbase[3 * DIN + d], w, a3);
        }
        qs4[t] = make_float4(a0 * SCALE, a1 * SCALE, a2 * SCALE, a3 * SCALE);
        wvL[t] = wv[t];
    }
    __syncthreads();

    // ---- phase 1: partial scores over this half's 128 h's (lo = k) ----
    {
        const float* kcol = kpT + b * H_ * TK + lo;
        int h0 = half * (H_ / 2);
        float s0 = 0.f, s1 = 0.f, s2 = 0.f, s3 = 0.f;
        #pragma unroll 4
        for (int hh = 0; hh < H_ / 2; ++hh) {
            int h = h0 + hh;
            float  kv  = kcol[h * TK];     // coalesced over k (256B/wave, L2-hot)
            float4 qv  = qs4[h];           // broadcast b128
            float  wvh = wvL[h];
            float u0 = qv.x + kv, u1 = qv.y + kv, u2 = qv.z + kv, u3 = qv.w + kv;
            float r0 = fast_rcp(fast_exp2(u0) + 1.f);
            float r1 = fast_rcp(fast_exp2(u1) + 1.f);
            float r2 = fast_rcp(fast_exp2(u2) + 1.f);
            float r3 = fast_rcp(fast_exp2(u3) + 1.f);
            s0 = fmaf(wvh, fmaf(-2.f, r0, 1.f), s0);
            s1 = fmaf(wvh, fmaf(-2.f, r1, 1.f), s1);
            s2 = fmaf(wvh, fmaf(-2.f, r2, 1.f), s2);
            s3 = fmaf(wvh, fmaf(-2.f, r3, 1.f), s3);
        }
        scoreP[half][0][lo] = s0;          // stride-1 -> conflict-free
        scoreP[half][1][lo] = s1;
        scoreP[half][2][lo] = s2;
        scoreP[half][3][lo] = s3;
    }
    __syncthreads();

    // ---- phase 2: waves 0..3 softmax rows q0..q0+3 (wave w = row w) ----
    if (t < 256) {
        int w    = t >> 6;
        int lane = t & 63;
        int vl   = valid_lens[b];
        float v0 = scoreP[0][w][lane      ] + scoreP[1][w][lane      ];
        float v1 = scoreP[0][w][lane +  64] + scoreP[1][w][lane +  64];
        float v2 = scoreP[0][w][lane + 128] + scoreP[1][w][lane + 128];
        float v3 = scoreP[0][w][lane + 192] + scoreP[1][w][lane + 192];
        v0 = (lane       < vl) ? v0 : NEG;
        v1 = (lane +  64 < vl) ? v1 : NEG;
        v2 = (lane + 128 < vl) ? v2 : NEG;
        v3 = (lane + 192 < vl) ? v3 : NEG;
        float m  = waveMax(fmaxf(fmaxf(v0, v1), fmaxf(v2, v3)));
        float p0 = fast_exp2((v0 - m) * LOG2E);
        float p1 = fast_exp2((v1 - m) * LOG2E);
        float p2 = fast_exp2((v2 - m) * LOG2E);
        float p3 = fast_exp2((v3 - m) * LOG2E);
        float dr = fast_rcp(waveSum(p0 + p1 + p2 + p3));
        // transposed store (8-way bank aliasing but only 4 writes/thread - negligible)
        ((float*)&attnT[lane      ])[w] = p0 * dr;
        ((float*)&attnT[lane +  64])[w] = p1 * dr;
        ((float*)&attnT[lane + 128])[w] = p2 * dr;
        ((float*)&attnT[lane + 192])[w] = p3 * dr;
    }
    __syncthreads();

    // ---- phase 3: partial out over this half's 128 k's (lo = v) ----
    {
        const float* vcol = values + b * TK * DV + lo;
        int k0 = half * (TK / 2);
        float o0 = 0.f, o1 = 0.f, o2 = 0.f, o3 = 0.f;
        #pragma unroll 8
        for (int kk = 0; kk < TK / 2; ++kk) {
            int k = k0 + kk;
            float  vv = vcol[k * DV];      // coalesced over v
            float4 a  = attnT[k];          // broadcast b128
            o0 = fmaf(a.x, vv, o0);
            o1 = fmaf(a.y, vv, o1);
            o2 = fmaf(a.z, vv, o2);
            o3 = fmaf(a.w, vv, o3);
        }
        if (half == 1) {                   // stash partials (reuse scoreP[1])
            scoreP[1][0][lo] = o0;
            scoreP[1][1][lo] = o1;
            scoreP[1][2][lo] = o2;
            scoreP[1][3][lo] = o3;
        }
        __syncthreads();
        if (half == 0) {
            float* orow = out + (b * TQ + q0) * DV + lo;
            orow[0]      = o0 + scoreP[1][0][lo];
            orow[DV]     = o1 + scoreP[1][1][lo];
            orow[2 * DV] = o2 + scoreP[1][2][lo];
            orow[3 * DV] = o3 + scoreP[1][3][lo];
        }
    }
}

extern "C" void kernel_launch(void* const* d_in, const int* in_sizes, int n_in,
                              void* d_out, int out_size, void* d_ws, size_t ws_size,
                              hipStream_t stream) {
    const float* queries    = (const float*)d_in[0];
    const float* keys       = (const float*)d_in[1];
    const float* values     = (const float*)d_in[2];
    const int*   valid_lens = (const int*)  d_in[3];
    const float* wq         = (const float*)d_in[4];
    const float* wk         = (const float*)d_in[5];
    const float* wv         = (const float*)d_in[6];
    float* out = (float*)d_out;

    float* kpT = (float*)d_ws;   // [B,H,TK] = 4 MiB

    proj_k_kernel<<<B_ * (H_ / HT), 256, 0, stream>>>(keys, wk, kpT);
    attn_kernel<<<B_ * (TQ / QT), 512, 0, stream>>>(queries, wq, kpT, values,
                                                    valid_lens, wv, out);
}

// Round 5
// 115.349 us; speedup vs baseline: 1.4170x; 1.0052x over previous
//
#include <hip/hip_runtime.h>

#define B_  16
#define TQ  128
#define TK  256
#define DIN 64
#define H_  256
#define DV  256
#define HT  8          // h-cols per proj_k block
#define QT  2          // q-rows per attn block
#define NEG -1000000.0f

// 2*log2(e): tanh(x) = 1 - 2/(1+e^{2x}) = 1 - 2*rcp(1 + exp2(SCALE*x))
#define SCALE  2.8853900817779268f
#define LOG2E  1.4426950408889634f

__device__ inline float fast_exp2(float x) { return __builtin_amdgcn_exp2f(x); }
__device__ inline float fast_rcp(float x)  { return __builtin_amdgcn_rcpf(x); }

// ---------------- Kernel B: kpT[b,h,k] = SCALE * sum_d keys[b,k,d]*wk[d,h] ----------------
// grid = B*(H/HT) = 512 blocks, 256 threads (t = k). Skips k >= ceil64(vl):
// those kpT entries are never read (phase-1 waves with k-base >= vl skip).
__global__ __launch_bounds__(256) void proj_k_kernel(
    const float* __restrict__ keys, const float* __restrict__ wk,
    float* __restrict__ kpT, const int* __restrict__ valid_lens)
{
    int b  = blockIdx.x >> 5;            // H_/HT == 32
    int h0 = (blockIdx.x & 31) * HT;
    int t  = threadIdx.x;                // k index
    int vlC = (valid_lens[b] + 63) & ~63;
    if (t >= vlC) return;                // wave-uniform (vlC multiple of 64)
    const float* krow = keys + (b * TK + t) * DIN;
    float acc[HT];
    #pragma unroll
    for (int hh = 0; hh < HT; ++hh) acc[hh] = 0.f;
    #pragma unroll 4
    for (int d = 0; d < DIN; ++d) {
        float kv = krow[d];
        #pragma unroll
        for (int hh = 0; hh < HT; ++hh)
            acc[hh] = fmaf(kv, wk[d * H_ + h0 + hh], acc[hh]);
    }
    #pragma unroll
    for (int hh = 0; hh < HT; ++hh)
        kpT[(b * H_ + h0 + hh) * TK + t] = acc[hh] * SCALE;
}

__device__ inline float waveMax(float v) {
    #pragma unroll
    for (int off = 32; off > 0; off >>= 1) v = fmaxf(v, __shfl_xor(v, off, 64));
    return v;
}
__device__ inline float waveSum(float v) {
    #pragma unroll
    for (int off = 32; off > 0; off >>= 1) v += __shfl_xor(v, off, 64);
    return v;
}

// ---------------- Kernel C: fused q-proj + scores(2 rows) + softmax + attn@V ----------------
// grid = B*(TQ/QT) = 1024 blocks, 512 threads -> 8192 waves = 100% wave-slot cap.
// Phase 1 splits h in halves across the two half-blocks; phase 3 splits k likewise.
// Wave-level valid_lens skipping: k-chunks >= vl produce exactly-0 softmax weights,
// so their scores (NEG) and PV contributions are skipped, ~halving issued work.
__global__ __launch_bounds__(512) void attn_kernel(
    const float* __restrict__ queries, const float* __restrict__ wq,
    const float* __restrict__ kpT,
    const float* __restrict__ values, const int* __restrict__ valid_lens,
    const float* __restrict__ wv, float* __restrict__ out)
{
    __shared__ float4 qw4[H_];            // (q0*S, q1*S, wv, 0): one b128 broadcast/iter
    __shared__ float  scoreP[2][QT][TK];  // per-half partial scores; [1] reused for out-partials
    __shared__ float2 attnT[TK];          // attn weights k-major (b64 broadcast in phase 3)

    // XCD swizzle: 2 batches per XCD slot -> ~1 MB working set per XCD L2.
    int bx   = blockIdx.x;
    int xcd  = bx & 7;
    int i    = bx >> 3;                   // 0..127
    int b    = xcd + 8 * (i & 1);
    int q0   = (i >> 1) * QT;             // 0,2,...,126
    int t    = threadIdx.x;               // 0..511
    int half = t >> 8;                    // 0/1: h-range (ph1) / k-range (ph3)
    int lo   = t & 255;                   // k (ph1) or v (ph3) index
    int vl   = valid_lens[b];

    // ---- phase 0: project QT=2 query rows (first 256 threads, t = h) ----
    if (t < 256) {
        const float* qbase = queries + (b * TQ + q0) * DIN;
        float a0 = 0.f, a1 = 0.f;
        #pragma unroll
        for (int d = 0; d < DIN; ++d) {
            float w = wq[d * H_ + t];                 // coalesced, L2-hot
            a0 = fmaf(qbase[d],       w, a0);         // uniform -> scalar loads
            a1 = fmaf(qbase[DIN + d], w, a1);
        }
        qw4[t] = make_float4(a0 * SCALE, a1 * SCALE, wv[t], 0.f);
    }
    __syncthreads();

    // ---- phase 1: partial scores over this half's 128 h's (lo = k) ----
    // Skip whole waves whose k-chunk is fully masked (wave-uniform: lo&192 uniform/wave).
    if ((lo & 192) < vl) {
        const float* kcol = kpT + b * H_ * TK + lo;
        int h0 = half * (H_ / 2);
        float s0 = 0.f, s1 = 0.f;
        #pragma unroll 4
        for (int hh = 0; hh < H_ / 2; ++hh) {
            int h = h0 + hh;
            float  kv = kcol[h * TK];      // coalesced over k, L2-hot
            float4 qv = qw4[h];            // broadcast b128
            float u0 = qv.x + kv, u1 = qv.y + kv;
            float r0 = fast_rcp(fast_exp2(u0) + 1.f);
            float r1 = fast_rcp(fast_exp2(u1) + 1.f);
            s0 = fmaf(qv.z, fmaf(-2.f, r0, 1.f), s0);
            s1 = fmaf(qv.z, fmaf(-2.f, r1, 1.f), s1);
        }
        scoreP[half][0][lo] = s0;          // stride-1 -> conflict-free
        scoreP[half][1][lo] = s1;
    }
    __syncthreads();

    // ---- phase 2: wave w (w<QT) softmaxes row q0+w ----
    // Masked entries may be garbage/NaN (skipped waves): ?: selects NEG first.
    if (t < 64 * QT) {
        int w    = t >> 6;
        int lane = t & 63;
        float v0 = scoreP[0][w][lane      ] + scoreP[1][w][lane      ];
        float v1 = scoreP[0][w][lane +  64] + scoreP[1][w][lane +  64];
        float v2 = scoreP[0][w][lane + 128] + scoreP[1][w][lane + 128];
        float v3 = scoreP[0][w][lane + 192] + scoreP[1][w][lane + 192];
        v0 = (lane       < vl) ? v0 : NEG;
        v1 = (lane +  64 < vl) ? v1 : NEG;
        v2 = (lane + 128 < vl) ? v2 : NEG;
        v3 = (lane + 192 < vl) ? v3 : NEG;
        float m  = waveMax(fmaxf(fmaxf(v0, v1), fmaxf(v2, v3)));
        // vl>0: masked p underflow to exactly 0 (matches ref). vl==0: m=NEG, p=1 -> uniform.
        float p0 = fast_exp2((v0 - m) * LOG2E);
        float p1 = fast_exp2((v1 - m) * LOG2E);
        float p2 = fast_exp2((v2 - m) * LOG2E);
        float p3 = fast_exp2((v3 - m) * LOG2E);
        float dr = fast_rcp(waveSum(p0 + p1 + p2 + p3));
        ((float*)&attnT[lane      ])[w] = p0 * dr;
        ((float*)&attnT[lane +  64])[w] = p1 * dr;
        ((float*)&attnT[lane + 128])[w] = p2 * dr;
        ((float*)&attnT[lane + 192])[w] = p3 * dr;
    }
    __syncthreads();

    // ---- phase 3: partial out over this half's k's, clipped to vl (lo = v) ----
    {
        int kLim = (vl == 0) ? TK : vl;    // vl==0: uniform weights, all k contribute
        int k0   = half * (TK / 2);
        int kEnd = min(k0 + TK / 2, kLim); // weights for k>=vl are exactly 0 -> skip
        const float* vcol = values + b * TK * DV + lo;
        float o0 = 0.f, o1 = 0.f;
        #pragma unroll 4
        for (int k = k0; k < kEnd; ++k) {
            float  vv = vcol[k * DV];      // coalesced over v
            float2 a  = attnT[k];          // broadcast b64
            o0 = fmaf(a.x, vv, o0);
            o1 = fmaf(a.y, vv, o1);
        }
        if (half == 1) {                   // stash partials (reuse scoreP[1])
            scoreP[1][0][lo] = o0;
            scoreP[1][1][lo] = o1;
        }
        __syncthreads();
        if (half == 0) {
            float* orow = out + (b * TQ + q0) * DV + lo;
            orow[0]  = o0 + scoreP[1][0][lo];
            orow[DV] = o1 + scoreP[1][1][lo];
        }
    }
}

extern "C" void kernel_launch(void* const* d_in, const int* in_sizes, int n_in,
                              void* d_out, int out_size, void* d_ws, size_t ws_size,
                              hipStream_t stream) {
    const float* queries    = (const float*)d_in[0];
    const float* keys       = (const float*)d_in[1];
    const float* values     = (const float*)d_in[2];
    const int*   valid_lens = (const int*)  d_in[3];
    const float* wq         = (const float*)d_in[4];
    const float* wk         = (const float*)d_in[5];
    const float* wv         = (const float*)d_in[6];
    float* out = (float*)d_out;

    float* kpT = (float*)d_ws;   // [B,H,TK] = 4 MiB

    proj_k_kernel<<<B_ * (H_ / HT), 256, 0, stream>>>(keys, wk, kpT, valid_lens);
    attn_kernel<<<B_ * (TQ / QT), 512, 0, stream>>>(queries, wq, kpT, values,
                                                    valid_lens, wv, out);
}

// Round 6
// 114.663 us; speedup vs baseline: 1.4255x; 1.0060x over previous
//
#include <hip/hip_runtime.h>

#define B_  16
#define TQ  128
#define TK  256
#define DIN 64
#define H_  256
#define DV  256
#define HT  8          // h-cols per proj_k block
#define QT  4          // q-rows per attn block
#define NW  8          // waves per attn block (512 threads)
#define NEG -1000000.0f

// tanh(x) = 1 - 2*rcp(1 + exp2(SCALE*x)), SCALE = 2*log2(e)
#define SCALE  2.8853900817779268f
#define LOG2E  1.4426950408889634f

__device__ inline float fast_exp2(float x) { return __builtin_amdgcn_exp2f(x); }
__device__ inline float fast_rcp(float x)  { return __builtin_amdgcn_rcpf(x); }

// ---------------- Kernel B: kpT[b,h,k] = SCALE * sum_d keys[b,k,d]*wk[d,h] ----------------
// grid = B*(H/HT) = 512 blocks, 256 threads (t = k). Skips k >= ceil64(vl): those
// entries stay 0xAA-poisoned (= -3.0e-13f, finite) and are masked to NEG downstream.
__global__ __launch_bounds__(256) void proj_k_kernel(
    const float* __restrict__ keys, const float* __restrict__ wk,
    float* __restrict__ kpT, const int* __restrict__ valid_lens)
{
    int b  = blockIdx.x >> 5;            // H_/HT == 32
    int h0 = (blockIdx.x & 31) * HT;
    int t  = threadIdx.x;                // k index
    int vlC = (valid_lens[b] + 63) & ~63;
    if (t >= vlC) return;                // wave-uniform exit
    const float* krow = keys + (b * TK + t) * DIN;
    float acc[HT];
    #pragma unroll
    for (int hh = 0; hh < HT; ++hh) acc[hh] = 0.f;
    #pragma unroll 4
    for (int d = 0; d < DIN; ++d) {
        float kv = krow[d];
        #pragma unroll
        for (int hh = 0; hh < HT; ++hh)
            acc[hh] = fmaf(kv, wk[d * H_ + h0 + hh], acc[hh]);
    }
    #pragma unroll
    for (int hh = 0; hh < HT; ++hh)
        kpT[(b * H_ + h0 + hh) * TK + t] = acc[hh] * SCALE;
}

__device__ inline float waveMax(float v) {
    #pragma unroll
    for (int off = 32; off > 0; off >>= 1) v = fmaxf(v, __shfl_xor(v, off, 64));
    return v;
}
__device__ inline float waveSum(float v) {
    #pragma unroll
    for (int off = 32; off > 0; off >>= 1) v += __shfl_xor(v, off, 64);
    return v;
}

// one tanh-score term for 4 k's (kv = float4 of k), one row (q-proj qr), weight wvh
#define ROW4(qr, sacc)                                            \
    {                                                             \
        float u0 = (qr) + kv.x, u1 = (qr) + kv.y;                 \
        float u2 = (qr) + kv.z, u3 = (qr) + kv.w;                 \
        float r0 = fast_rcp(fast_exp2(u0) + 1.f);                 \
        float r1 = fast_rcp(fast_exp2(u1) + 1.f);                 \
        float r2 = fast_rcp(fast_exp2(u2) + 1.f);                 \
        float r3 = fast_rcp(fast_exp2(u3) + 1.f);                 \
        sacc.x = fmaf(wvh, fmaf(-2.f, r0, 1.f), sacc.x);          \
        sacc.y = fmaf(wvh, fmaf(-2.f, r1, 1.f), sacc.y);          \
        sacc.z = fmaf(wvh, fmaf(-2.f, r2, 1.f), sacc.z);          \
        sacc.w = fmaf(wvh, fmaf(-2.f, r3, 1.f), sacc.w);          \
    }

// ---------------- Kernel C: fused q-proj + scores(4 rows) + softmax + attn@V ----------------
// grid = B*(TQ/QT) = 512 blocks, 512 threads (8 waves -> 16 waves/CU).
// Phase 1: wave w owns h in [32w,32w+32); lane l covers k=4l..4l+3 via one float4 load
// (1 KB/wave/iter) feeding 16 tanh -> ~270 issue-cyc per load. All waves always busy:
// critical path is vl-independent -> no intra-block idling, no cross-XCD stragglers.
__global__ __launch_bounds__(512) void attn_kernel(
    const float* __restrict__ queries, const float* __restrict__ wq,
    const float* __restrict__ kpT,
    const float* __restrict__ values, const int* __restrict__ valid_lens,
    const float* __restrict__ wv, float* __restrict__ out)
{
    __shared__ float2 qs2[2][H_];          // [rowpair][h] scaled q-proj
    __shared__ float  wvL[H_];
    __shared__ float  scoreP[NW][QT][TK];  // 32 KB; [0] reused for phase-3 partials
    __shared__ float  attnT[TK][QT];       // k-major, float4-readable per k

    // XCD swizzle: 2 batches per XCD slot -> ~1 MB hot set per XCD L2.
    int bx = blockIdx.x;
    int xcd = bx & 7;
    int i   = bx >> 3;                     // 0..63
    int b   = xcd + 8 * (i & 1);
    int q0  = (i >> 1) * QT;               // 0,4,...,124
    int t   = threadIdx.x;                 // 0..511
    int w   = t >> 6, l = t & 63;
    int vl  = valid_lens[b];

    // ---- phase 0: project 4 query rows; half-block rp handles row pair rp ----
    {
        int h = t & 255, rp = t >> 8;
        const float* qbase = queries + (b * TQ + q0 + rp * 2) * DIN;  // uniform -> s_load
        float a0 = 0.f, a1 = 0.f;
        #pragma unroll
        for (int d = 0; d < DIN; ++d) {
            float ww = wq[d * H_ + h];                // coalesced, L2-hot
            a0 = fmaf(qbase[d],       ww, a0);
            a1 = fmaf(qbase[DIN + d], ww, a1);
        }
        qs2[rp][h] = make_float2(a0 * SCALE, a1 * SCALE);
        if (t < 256) wvL[h] = wv[h];
    }
    __syncthreads();

    // ---- phase 1: wave w covers its 32-wide h-split; lane l covers k=4l..4l+3 ----
    {
        const float4* kp4 = (const float4*)(kpT + (size_t)b * H_ * TK);
        float4 s0 = {0,0,0,0}, s1 = {0,0,0,0}, s2 = {0,0,0,0}, s3 = {0,0,0,0};
        int h0 = w * (H_ / NW);
        #pragma unroll 2
        for (int hh = 0; hh < H_ / NW; ++hh) {
            int h = h0 + hh;
            float4 kv  = kp4[h * (TK / 4) + l];   // coalesced 1 KB/wave, L2-hot
            float2 qA  = qs2[0][h];               // broadcast b64 (rows 0,1)
            float2 qB  = qs2[1][h];               // broadcast b64 (rows 2,3)
            float  wvh = wvL[h];
            ROW4(qA.x, s0);
            ROW4(qA.y, s1);
            ROW4(qB.x, s2);
            ROW4(qB.y, s3);
        }
        ((float4*)&scoreP[w][0][0])[l] = s0;      // b128 stores
        ((float4*)&scoreP[w][1][0])[l] = s1;
        ((float4*)&scoreP[w][2][0])[l] = s2;
        ((float4*)&scoreP[w][3][0])[l] = s3;
    }
    __syncthreads();

    // ---- phase 2: wave r (r<QT) softmaxes row q0+r; lane covers k=4l..4l+3 ----
    if (t < 64 * QT) {
        int r = w;
        float4 v = {0,0,0,0};
        #pragma unroll
        for (int s = 0; s < NW; ++s) {
            float4 ps = ((const float4*)&scoreP[s][r][0])[l];
            v.x += ps.x; v.y += ps.y; v.z += ps.z; v.w += ps.w;
        }
        int k0 = 4 * l;
        v.x = (k0     < vl) ? v.x : NEG;
        v.y = (k0 + 1 < vl) ? v.y : NEG;
        v.z = (k0 + 2 < vl) ? v.z : NEG;
        v.w = (k0 + 3 < vl) ? v.w : NEG;
        float m  = waveMax(fmaxf(fmaxf(v.x, v.y), fmaxf(v.z, v.w)));
        // vl>0: masked p underflows to exactly 0 (matches ref). vl==0: all equal -> uniform.
        float p0 = fast_exp2((v.x - m) * LOG2E);
        float p1 = fast_exp2((v.y - m) * LOG2E);
        float p2 = fast_exp2((v.z - m) * LOG2E);
        float p3 = fast_exp2((v.w - m) * LOG2E);
        float dr = fast_rcp(waveSum(p0 + p1 + p2 + p3));
        attnT[k0    ][r] = p0 * dr;
        attnT[k0 + 1][r] = p1 * dr;
        attnT[k0 + 2][r] = p2 * dr;
        attnT[k0 + 3][r] = p3 * dr;
    }
    __syncthreads();

    // ---- phase 3: half-block splits k-range, clipped to vl (weights for k>=vl are 0) ----
    {
        int half = t >> 8, v = t & 255;
        int kLim = (vl == 0) ? TK : vl;        // vl==0: uniform weights over all k
        int kBeg = half * (TK / 2);
        int kEnd = min(kBeg + TK / 2, kLim);   // half1 empty when kLim<=128
        const float*  vcol = values + (size_t)b * TK * DV + v;
        const float4* at4  = (const float4*)attnT;
        float o0 = 0.f, o1 = 0.f, o2 = 0.f, o3 = 0.f;
        #pragma unroll 4
        for (int k = kBeg; k < kEnd; ++k) {
            float  vv = vcol[k * DV];          // coalesced over v
            float4 a  = at4[k];                // broadcast b128
            o0 = fmaf(a.x, vv, o0);
            o1 = fmaf(a.y, vv, o1);
            o2 = fmaf(a.z, vv, o2);
            o3 = fmaf(a.w, vv, o3);
        }
        if (half == 1) {                       // stash partials (reuse scoreP[0])
            scoreP[0][0][v] = o0;
            scoreP[0][1][v] = o1;
            scoreP[0][2][v] = o2;
            scoreP[0][3][v] = o3;
        }
        __syncthreads();
        if (half == 0) {
            float* orow = out + (size_t)(b * TQ + q0) * DV + v;
            orow[0]      = o0 + scoreP[0][0][v];
            orow[DV]     = o1 + scoreP[0][1][v];
            orow[2 * DV] = o2 + scoreP[0][2][v];
            orow[3 * DV] = o3 + scoreP[0][3][v];
        }
    }
}

extern "C" void kernel_launch(void* const* d_in, const int* in_sizes, int n_in,
                              void* d_out, int out_size, void* d_ws, size_t ws_size,
                              hipStream_t stream) {
    const float* queries    = (const float*)d_in[0];
    const float* keys       = (const float*)d_in[1];
    const float* values     = (const float*)d_in[2];
    const int*   valid_lens = (const int*)  d_in[3];
    const float* wq         = (const float*)d_in[4];
    const float* wk         = (const float*)d_in[5];
    const float* wv         = (const float*)d_in[6];
    float* out = (float*)d_out;

    float* kpT = (float*)d_ws;   // [B,H,TK] = 4 MiB

    proj_k_kernel<<<B_ * (H_ / HT), 256, 0, stream>>>(keys, wk, kpT, valid_lens);
    attn_kernel<<<B_ * (TQ / QT), 512, 0, stream>>>(queries, wq, kpT, values,
                                                    valid_lens, wv, out);
}